// Round 1
// baseline (474.867 us; speedup 1.0000x reference)
//
#include <hip/hip_runtime.h>
#include <hip/hip_bf16.h>

// Problem constants (from reference): B=64, C=256, H=64, W=64, EMB=512, NH=4, HD=64.
// Key algebraic fact: K/V sequence length is 1 -> softmax over a size-1 axis == 1.0
// identically, so q / layernorm / wk are dead code. The whole block reduces to:
//   v_in[b]     = cond_emb[b] @ kv_w[C:2C].T + kv_b[C:2C]          (64 x 256)
//   v_row[b]    = v_in[b] @ wv.T + bv,  wv = in_proj_w[2C:3C]      (64 x 256)
//   attn_out[b] = v_row[b] @ out_w.T + out_b                       (64 x 256)
//   y[b,c,h,w]  = x[b,c,h,w] + attn_out[b,c]
// Roofline: elementwise pass reads+writes 2 * 268 MB -> ~85 us at 6.3 TB/s.

#define Bc 64
#define Cc 256
#define EMBc 512
#define HWc 4096

// One block per batch element, 256 threads.
__global__ __launch_bounds__(256) void attn_vec_kernel(
    const float* __restrict__ cond_emb,   // (B, EMB)
    const float* __restrict__ in_proj_w,  // (3C, C)
    const float* __restrict__ in_proj_b,  // (3C,)
    const float* __restrict__ out_w,      // (C, C)
    const float* __restrict__ out_b,      // (C,)
    const float* __restrict__ kv_w,       // (2C, EMB)
    const float* __restrict__ kv_b,       // (2C,)
    float* __restrict__ attn_out)         // (B, C) scratch
{
    __shared__ float s_cond[EMBc];
    __shared__ float s_vin[Cc];
    __shared__ float s_vrow[Cc];

    const int b   = blockIdx.x;
    const int tid = threadIdx.x;

    // stage cond_emb row
    s_cond[tid]       = cond_emb[b * EMBc + tid];
    s_cond[tid + 256] = cond_emb[b * EMBc + tid + 256];
    __syncthreads();

    // v_in[tid] = cond_emb[b] . kv_w[C+tid, :] + kv_b[C+tid]
    {
        float acc = kv_b[Cc + tid];
        const float* wrow = kv_w + (size_t)(Cc + tid) * EMBc;
        #pragma unroll 8
        for (int e = 0; e < EMBc; ++e) acc += wrow[e] * s_cond[e];
        s_vin[tid] = acc;
    }
    __syncthreads();

    // v_row[tid] = v_in . wv[tid, :] + bv[tid],  wv row = in_proj_w[2C + tid]
    {
        float acc = in_proj_b[2 * Cc + tid];
        const float* wrow = in_proj_w + (size_t)(2 * Cc + tid) * Cc;
        #pragma unroll 8
        for (int j = 0; j < Cc; ++j) acc += wrow[j] * s_vin[j];
        s_vrow[tid] = acc;
    }
    __syncthreads();

    // attn_out[b, tid] = v_row . out_w[tid, :] + out_b[tid]
    {
        float acc = out_b[tid];
        const float* wrow = out_w + (size_t)tid * Cc;
        #pragma unroll 8
        for (int i = 0; i < Cc; ++i) acc += wrow[i] * s_vrow[i];
        attn_out[(size_t)b * Cc + tid] = acc;
    }
}

// y = x + attn_out[b,c] broadcast; one float4 per thread.
// idx4 in [0, B*C*HW/4); plane (b,c) has HW/4 = 1024 float4s -> bc = idx4 >> 10.
__global__ __launch_bounds__(256) void add_broadcast_kernel(
    const float4* __restrict__ x4,
    const float* __restrict__ attn_out,
    float4* __restrict__ y4)
{
    const size_t idx4 = (size_t)blockIdx.x * blockDim.x + threadIdx.x;
    const int bc = (int)(idx4 >> 10);
    const float a = attn_out[bc];
    float4 v = x4[idx4];
    v.x += a; v.y += a; v.z += a; v.w += a;
    y4[idx4] = v;
}

extern "C" void kernel_launch(void* const* d_in, const int* in_sizes, int n_in,
                              void* d_out, int out_size, void* d_ws, size_t ws_size,
                              hipStream_t stream) {
    const float* x         = (const float*)d_in[0];
    const float* cond_emb  = (const float*)d_in[1];
    // d_in[2] ln_gamma, d_in[3] ln_beta: dead (only feed q, which softmax erases)
    const float* in_proj_w = (const float*)d_in[4];
    const float* in_proj_b = (const float*)d_in[5];
    const float* out_w     = (const float*)d_in[6];
    const float* out_b     = (const float*)d_in[7];
    const float* kv_w      = (const float*)d_in[8];
    const float* kv_b      = (const float*)d_in[9];

    float* attn_out = (float*)d_ws;  // 64*256 floats = 64 KB
    float* y        = (float*)d_out;

    attn_vec_kernel<<<Bc, 256, 0, stream>>>(cond_emb, in_proj_w, in_proj_b,
                                            out_w, out_b, kv_w, kv_b, attn_out);

    const size_t n4 = (size_t)Bc * Cc * HWc / 4;  // 16,777,216
    const int blocks = (int)(n4 / 256);           // 65,536
    add_broadcast_kernel<<<blocks, 256, 0, stream>>>(
        (const float4*)x, attn_out, (float4*)y);
}

// Round 2
// 463.731 us; speedup vs baseline: 1.0240x; 1.0240x over previous
//
#include <hip/hip_runtime.h>
#include <hip/hip_bf16.h>

// Problem constants (from reference): B=64, C=256, H=64, W=64, EMB=512, NH=4, HD=64.
// Key algebraic fact: K/V sequence length is 1 -> softmax over a size-1 axis == 1.0
// identically, so q / layernorm / wk are dead code. The whole block reduces to:
//   v_in[b]     = cond_emb[b] @ kv_w[C:2C].T + kv_b[C:2C]          (64 x 256)
//   v_row[b]    = v_in[b] @ wv.T + bv,  wv = in_proj_w[2C:3C]      (64 x 256)
//   attn_out[b] = v_row[b] @ out_w.T + out_b                       (64 x 256)
//   y[b,c,h,w]  = x[b,c,h,w] + attn_out[b,c]
// Structural floor: elementwise pass reads+writes 2 * 268 MB -> ~85 us at 6.3 TB/s.

#define Bc 64
#define Cc 256
#define EMBc 512
#define HWc 4096

// One block per batch element, 256 threads, float4 weight-row loads.
__global__ __launch_bounds__(256) void attn_vec_kernel(
    const float* __restrict__ cond_emb,   // (B, EMB)
    const float* __restrict__ in_proj_w,  // (3C, C)
    const float* __restrict__ in_proj_b,  // (3C,)
    const float* __restrict__ out_w,      // (C, C)
    const float* __restrict__ out_b,      // (C,)
    const float* __restrict__ kv_w,       // (2C, EMB)
    const float* __restrict__ kv_b,       // (2C,)
    float* __restrict__ attn_out)         // (B, C) scratch
{
    __shared__ float4 s_cond[EMBc / 4];   // 128 float4
    __shared__ float4 s_vin[Cc / 4];      // 64 float4
    __shared__ float4 s_vrow[Cc / 4];     // 64 float4

    const int b   = blockIdx.x;
    const int tid = threadIdx.x;

    // stage cond_emb row (512 floats = 128 float4)
    if (tid < EMBc / 4)
        s_cond[tid] = ((const float4*)(cond_emb + (size_t)b * EMBc))[tid];
    __syncthreads();

    // v_in[tid] = cond_emb[b] . kv_w[C+tid, :] + kv_b[C+tid]
    {
        const float4* wrow = (const float4*)(kv_w + (size_t)(Cc + tid) * EMBc);
        float acc = kv_b[Cc + tid];
        #pragma unroll 8
        for (int e = 0; e < EMBc / 4; ++e) {
            float4 w = wrow[e], c = s_cond[e];
            acc += w.x * c.x + w.y * c.y + w.z * c.z + w.w * c.w;
        }
        ((float*)s_vin)[tid] = acc;
    }
    __syncthreads();

    // v_row[tid] = v_in . wv[tid, :] + bv[tid],  wv row = in_proj_w[2C + tid]
    {
        const float4* wrow = (const float4*)(in_proj_w + (size_t)(2 * Cc + tid) * Cc);
        float acc = in_proj_b[2 * Cc + tid];
        #pragma unroll 8
        for (int j = 0; j < Cc / 4; ++j) {
            float4 w = wrow[j], c = s_vin[j];
            acc += w.x * c.x + w.y * c.y + w.z * c.z + w.w * c.w;
        }
        ((float*)s_vrow)[tid] = acc;
    }
    __syncthreads();

    // attn_out[b, tid] = v_row . out_w[tid, :] + out_b[tid]
    {
        const float4* wrow = (const float4*)(out_w + (size_t)tid * Cc);
        float acc = out_b[tid];
        #pragma unroll 8
        for (int i = 0; i < Cc / 4; ++i) {
            float4 w = wrow[i], c = s_vrow[i];
            acc += w.x * c.x + w.y * c.y + w.z * c.z + w.w * c.w;
        }
        attn_out[(size_t)b * Cc + tid] = acc;
    }
}

// y = x + attn_out[b,c]; one float4 per thread.
// A 256-thread block covers 256 float4 = 1/4 of one (b,c) plane (1024 float4),
// so the plane index is block-uniform: bc = blockIdx.x >> 2  ->  scalar load.
__global__ __launch_bounds__(256) void add_broadcast_kernel(
    const float4* __restrict__ x4,
    const float* __restrict__ attn_out,
    float4* __restrict__ y4)
{
    const int bc  = (int)(blockIdx.x >> 2);     // uniform across the block
    const float a = attn_out[bc];               // s_load, broadcast
    const size_t idx4 = (size_t)blockIdx.x * 256 + threadIdx.x;
    float4 v = x4[idx4];
    v.x += a; v.y += a; v.z += a; v.w += a;
    y4[idx4] = v;
}

extern "C" void kernel_launch(void* const* d_in, const int* in_sizes, int n_in,
                              void* d_out, int out_size, void* d_ws, size_t ws_size,
                              hipStream_t stream) {
    const float* x         = (const float*)d_in[0];
    const float* cond_emb  = (const float*)d_in[1];
    // d_in[2] ln_gamma, d_in[3] ln_beta: dead (only feed q, which softmax erases)
    const float* in_proj_w = (const float*)d_in[4];
    const float* in_proj_b = (const float*)d_in[5];
    const float* out_w     = (const float*)d_in[6];
    const float* out_b     = (const float*)d_in[7];
    const float* kv_w      = (const float*)d_in[8];
    const float* kv_b      = (const float*)d_in[9];

    float* attn_out = (float*)d_ws;  // 64*256 floats = 64 KB
    float* y        = (float*)d_out;

    attn_vec_kernel<<<Bc, 256, 0, stream>>>(cond_emb, in_proj_w, in_proj_b,
                                            out_w, out_b, kv_w, kv_b, attn_out);

    const size_t n4 = (size_t)Bc * Cc * HWc / 4;  // 16,777,216 float4
    const int blocks = (int)(n4 / 256);           // 65,536 (4 per (b,c) plane)
    add_broadcast_kernel<<<blocks, 256, 0, stream>>>(
        (const float4*)x, attn_out, (float4*)y);
}